// Round 12
// baseline (244.627 us; speedup 1.0000x reference)
//
#include <hip/hip_runtime.h>
#include <math.h>

#define HH 352
#define WW 352
#define IMG (HH * WW)          // 123904
#define NPIX (8 * IMG)         // 991232 (B=8)
#define NG (NPIX / 4)          // 247808 float4 pixel-groups
#define IMG4 (IMG / 4)         // 30976 groups per image
#define WB (WW / 4)            // 88 blocks per row
#define THREADS 256
#define GBLK (NG / THREADS)    // 968 exactly

typedef float f4 __attribute__((ext_vector_type(4)));
typedef int   i4 __attribute__((ext_vector_type(4)));

__device__ __forceinline__ float rcpf_(float x) { return __builtin_amdgcn_rcpf(x); }

__device__ __forceinline__ f4 exp4(f4 x) {
    f4 r;
    #pragma unroll
    for (int i = 0; i < 4; i++) r[i] = __expf(x[i]);
    return r;
}
__device__ __forceinline__ f4 log4(f4 x) {
    f4 r;
    #pragma unroll
    for (int i = 0; i < 4; i++) r[i] = __logf(x[i]);
    return r;
}
__device__ __forceinline__ f4 rcp4(f4 x) {
    f4 r;
    #pragma unroll
    for (int i = 0; i < 4; i++) r[i] = rcpf_(x[i]);
    return r;
}
__device__ __forceinline__ f4 min4(f4 a, f4 b) {
    f4 r;
    #pragma unroll
    for (int i = 0; i < 4; i++) r[i] = fminf(a[i], b[i]);
    return r;
}
__device__ __forceinline__ f4 min4s(f4 a, float b) {
    f4 r;
    #pragma unroll
    for (int i = 0; i < 4; i++) r[i] = fminf(a[i], b);
    return r;
}
__device__ __forceinline__ f4 max4s(f4 a, float b) {
    f4 r;
    #pragma unroll
    for (int i = 0; i < 4; i++) r[i] = fmaxf(a[i], b);
    return r;
}

__device__ __forceinline__ f4 loadu4(const float* p) {   // dword-aligned float4
    f4 v;
    __builtin_memcpy(&v, p, 16);
    return v;
}

__device__ __forceinline__ float wave_reduce_f(float v) {
    #pragma unroll
    for (int off = 32; off > 0; off >>= 1) v += __shfl_down(v, off, 64);
    return v;
}
__device__ __forceinline__ int wave_reduce_i(int v) {
    #pragma unroll
    for (int off = 32; off > 0; off >>= 1) v += __shfl_down(v, off, 64);
    return v;
}

__device__ __forceinline__ void block_acc(float v, double* dst) {
    v = wave_reduce_f(v);
    __shared__ float sm[4];
    int lane = threadIdx.x & 63, wid = threadIdx.x >> 6;
    if (lane == 0) sm[wid] = v;
    __syncthreads();
    if (threadIdx.x == 0)
        atomicAdd(dst, (double)(sm[0] + sm[1] + sm[2] + sm[3]));
}

// Pack con (int32 0/1, 8 planes) -> 1 byte/pixel: packed[g] holds 4 pixels.
__global__ void k_pack(const int* __restrict__ con,
                       unsigned int* __restrict__ packed) {
    int g = blockIdx.x * THREADS + threadIdx.x;
    int b = g / IMG4;
    int r4 = g - b * IMG4;
    const int* cb = con + (size_t)b * 8 * IMG + 4 * (size_t)r4;
    unsigned int pk = 0;
    #pragma unroll
    for (int k = 0; k < 8; k++) {
        i4 c = *(const i4*)(cb + (size_t)k * IMG);
        pk |= ((unsigned)c[0]) << k;
        pk |= ((unsigned)c[1]) << (8 + k);
        pk |= ((unsigned)c[2]) << (16 + k);
        pk |= ((unsigned)c[3]) << (24 + k);
    }
    packed[g] = pk;
}

// One kernel, 5 independent slices: y=0 edge loss, y=1..4 sal tensor y-1.
__global__ __launch_bounds__(THREADS, 4) void k_main(
        const float* __restrict__ up_edge,
        const float* __restrict__ up_sal,
        const float* __restrict__ up_sal_f,
        const float* __restrict__ target,
        const unsigned int* __restrict__ packed,
        double* __restrict__ acc,            // [0]=S_pos,[1]=S_neg,[2]=sal_l
        unsigned int* __restrict__ npos) {
    int g = blockIdx.x * THREADS + threadIdx.x;   // pixel-group
    int y = blockIdx.y;
    int b = g / IMG4;
    int r4 = g - b * IMG4;

    unsigned int pk = packed[g];
    unsigned int byte_[4];
    f4 em4;
    #pragma unroll
    for (int j = 0; j < 4; j++) {
        unsigned int by = (pk >> (8 * j)) & 0xffu;
        byte_[j] = by;
        em4[j] = (by != 0u && by != 0xffu) ? 1.0f : 0.0f;
    }

    if (y == 0) {
        // ---- edge slice: weight-factored bce2d_new over 3 logit maps ----
        f4 x[3];
        #pragma unroll
        for (int i = 0; i < 3; i++)
            x[i] = *(const f4*)(up_edge + (size_t)i * NPIX + 4 * (size_t)g);
        float sp = 0.0f, sn = 0.0f; int cnt = 0;
        #pragma unroll
        for (int j = 0; j < 4; j++) {
            float em = em4[j], ce = 0.0f;
            #pragma unroll
            for (int i = 0; i < 3; i++) {
                float xx = x[i][j];
                ce += fmaxf(xx, 0.0f) - xx * em + __logf(1.0f + __expf(-fabsf(xx)));
            }
            sp += em * ce;
            sn += (1.0f - em) * ce;
            cnt += (int)em;
        }
        sp = wave_reduce_f(sp);
        sn = wave_reduce_f(sn);
        cnt = wave_reduce_i(cnt);
        __shared__ float smp[4], smn[4];
        __shared__ int smc[4];
        int lane = threadIdx.x & 63, wid = threadIdx.x >> 6;
        if (lane == 0) { smp[wid] = sp; smn[wid] = sn; smc[wid] = cnt; }
        __syncthreads();
        if (threadIdx.x == 0) {
            atomicAdd(acc + 0, (double)(smp[0] + smp[1] + smp[2] + smp[3]));
            atomicAdd(acc + 1, (double)(smn[0] + smn[1] + smn[2] + smn[3]));
            atomicAdd(npos, (unsigned int)(smc[0] + smc[1] + smc[2] + smc[3]));
        }
        return;
    }

    // ---- sal slice for tensor s4 = y-1, fully f4-vectorized over j ----
    int s4 = y - 1;
    int h  = r4 / WB;
    int wb = r4 - h * WB;
    int ro = 4 * wb;
    const float* tb = (s4 < 2) ? (up_sal + (size_t)s4 * 8 * NPIX)
                               : (up_sal_f + (size_t)(s4 - 2) * 8 * NPIX);
    const float* base = tb + (size_t)b * 8 * IMG;

    f4 tgt = *(const f4*)(target + 4 * (size_t)g);
    float cmL = (wb != 0)      ? 1.0f : 0.0f;
    float cmR = (wb != WB - 1) ? 1.0f : 0.0f;

    const int drs[8] = {-1, -1, -1,  0, 0,  1, 1, 1};
    const int dcs[8] = {-1,  0,  1, -1, 1, -1, 0, 1};

    f4 xc[8], xn[8];
    float hok[8];
    #pragma unroll
    for (int k = 0; k < 8; k++) {
        xc[k] = *(const f4*)(base + k * IMG + 4 * r4);      // 16B-aligned
        int h2  = h + drs[k];
        int h2c = min(max(h2, 0), HH - 1);
        int off = (7 - k) * IMG + h2c * WW + ro + dcs[k];   // 32-bit
        off = max(off, 0);
        off = min(off, 8 * IMG - 4);
        xn[k] = loadu4(base + off);
        hok[k] = ((unsigned)h2 < (unsigned)HH) ? 1.0f : 0.0f;
    }

    f4 vsum = (f4)0.0f, vmin4 = (f4)1e30f, vb = (f4)0.0f, pb = (f4)0.0f;
    #pragma unroll
    for (int k = 0; k < 8; k++) {
        f4 tm;
        #pragma unroll
        for (int j = 0; j < 4; j++) tm[j] = (float)((byte_[j] >> k) & 1u);
        f4 ok4 = (f4){hok[k], hok[k], hok[k], hok[k]};
        if (dcs[k] == -1) ok4[0] *= cmL;
        if (dcs[k] ==  1) ok4[3] *= cmR;

        f4 e  = exp4(-xc[k]);
        f4 q1 = e + 1.0f;
        f4 sc = log4(q1);                 // -log sigmoid(xc)
        f4 en = exp4(-xn[k]);
        f4 q  = q1 * (en + 1.0f);
        f4 v  = ok4 * rcp4(q);            // vote = sig(xc)*sig(xn)*mask

        vsum += v;
        vmin4 = min4(vmin4, v);
        // t=1: -log v ; t=0: -log(1-v) — arithmetic select, one log
        f4 arg = (1.0f - v) + tm * (2.0f * v - 1.0f);
        vb += min4s(-log4(arg), 100.0f);
        pb += min4s(sc + (1.0f - tm) * xc[k], 100.0f);
    }

    f4 glo = vsum * 0.125f;
    f4 dec = glo + em4 * ((1.0f - vmin4) - glo);
    f4 lgd  = max4s(log4(dec), -100.0f);
    f4 lg1d = max4s(log4(1.0f - dec), -100.0f);
    f4 lf = -(tgt * lgd + (1.0f - tgt) * lg1d) + 0.2f * vb + 0.8f * pb;
    float local = lf[0] + lf[1] + lf[2] + lf[3];
    block_acc(local, acc + 2);
}

__global__ void k_final(const double* __restrict__ acc,
                        const unsigned int* __restrict__ npos,
                        float* __restrict__ out) {
    if (threadIdx.x == 0) {
        double np_  = (double)(*npos);
        double tot  = (double)NPIX;
        double nn   = tot - np_;
        double wpos = nn / tot;
        double wneg = 1.1 * np_ / tot;
        double e  = wpos * acc[0] + wneg * acc[1];
        double sl = acc[2];
        double l  = e + sl;
        out[0] = (float)l;
        out[1] = (float)e;
        out[2] = (float)sl;
        out[3] = (float)l;
    }
}

extern "C" void kernel_launch(void* const* d_in, const int* in_sizes, int n_in,
                              void* d_out, int out_size, void* d_ws, size_t ws_size,
                              hipStream_t stream) {
    const float* up_edge  = (const float*)d_in[0];  // [3,B,1,H,W]
    const float* up_sal   = (const float*)d_in[1];  // [2,B,8,H,W]
    const float* up_sal_f = (const float*)d_in[2];  // [2,B,8,H,W]
    const float* target   = (const float*)d_in[3];  // [B,1,H,W]
    const int*   con      = (const int*)d_in[4];    // [B,8,H,W]
    float* out = (float*)d_out;

    // ws: acc[0..2] doubles (S_pos, S_neg, sal_l); npos uint at +24;
    //     packed con plane (NG uints) at +64
    double*       acc    = (double*)d_ws;
    unsigned int* npos   = (unsigned int*)((char*)d_ws + 24);
    unsigned int* packed = (unsigned int*)((char*)d_ws + 64);

    hipMemsetAsync(d_ws, 0, 64, stream);
    k_pack<<<GBLK, THREADS, 0, stream>>>(con, packed);
    k_main<<<dim3(GBLK, 5), THREADS, 0, stream>>>(up_edge, up_sal, up_sal_f,
                                                  target, packed, acc, npos);
    k_final<<<1, 64, 0, stream>>>(acc, npos, out);
}

// Round 13
// 238.013 us; speedup vs baseline: 1.0278x; 1.0278x over previous
//
#include <hip/hip_runtime.h>
#include <math.h>

#define HH 352
#define WW 352
#define IMG (HH * WW)          // 123904
#define NPIX (8 * IMG)         // 991232 (B=8)
#define NG (NPIX / 4)          // 247808 float4 pixel-groups
#define IMG4 (IMG / 4)         // 30976 groups per image
#define WB (WW / 4)            // 88 blocks per row
#define THREADS 256
#define GBLK (NG / THREADS)    // 968 exactly

typedef float f4 __attribute__((ext_vector_type(4)));
typedef int   i4 __attribute__((ext_vector_type(4)));

__device__ __forceinline__ float rcpf_(float x) { return __builtin_amdgcn_rcpf(x); }

__device__ __forceinline__ f4 exp4(f4 x) {
    f4 r;
    #pragma unroll
    for (int i = 0; i < 4; i++) r[i] = __expf(x[i]);
    return r;
}
__device__ __forceinline__ f4 log4(f4 x) {
    f4 r;
    #pragma unroll
    for (int i = 0; i < 4; i++) r[i] = __logf(x[i]);
    return r;
}
__device__ __forceinline__ f4 rcp4(f4 x) {
    f4 r;
    #pragma unroll
    for (int i = 0; i < 4; i++) r[i] = rcpf_(x[i]);
    return r;
}
__device__ __forceinline__ f4 min4(f4 a, f4 b) {
    f4 r;
    #pragma unroll
    for (int i = 0; i < 4; i++) r[i] = fminf(a[i], b[i]);
    return r;
}
__device__ __forceinline__ f4 min4s(f4 a, float b) {
    f4 r;
    #pragma unroll
    for (int i = 0; i < 4; i++) r[i] = fminf(a[i], b);
    return r;
}
__device__ __forceinline__ f4 max4s(f4 a, float b) {
    f4 r;
    #pragma unroll
    for (int i = 0; i < 4; i++) r[i] = fmaxf(a[i], b);
    return r;
}

__device__ __forceinline__ f4 loadu4(const float* p) {   // dword-aligned float4
    f4 v;
    __builtin_memcpy(&v, p, 16);
    return v;
}

__device__ __forceinline__ float wave_reduce_f(float v) {
    #pragma unroll
    for (int off = 32; off > 0; off >>= 1) v += __shfl_down(v, off, 64);
    return v;
}
__device__ __forceinline__ int wave_reduce_i(int v) {
    #pragma unroll
    for (int off = 32; off > 0; off >>= 1) v += __shfl_down(v, off, 64);
    return v;
}

__device__ __forceinline__ void block_acc(float v, double* dst) {
    v = wave_reduce_f(v);
    __shared__ float sm[4];
    int lane = threadIdx.x & 63, wid = threadIdx.x >> 6;
    if (lane == 0) sm[wid] = v;
    __syncthreads();
    if (threadIdx.x == 0)
        atomicAdd(dst, (double)(sm[0] + sm[1] + sm[2] + sm[3]));
}

// Pack con (int32 0/1, 8 planes) -> 1 byte/pixel; also zero the accumulators
// (replaces the hipMemsetAsync node).
__global__ void k_pack(const int* __restrict__ con,
                       unsigned int* __restrict__ packed,
                       double* __restrict__ acc,
                       unsigned int* __restrict__ npos) {
    int g = blockIdx.x * THREADS + threadIdx.x;
    if (g < 3) acc[g] = 0.0;
    if (g == 3) *npos = 0u;
    int b = g / IMG4;
    int r4 = g - b * IMG4;
    const int* cb = con + (size_t)b * 8 * IMG + 4 * (size_t)r4;
    unsigned int pk = 0;
    #pragma unroll
    for (int k = 0; k < 8; k++) {
        i4 c = *(const i4*)(cb + (size_t)k * IMG);
        pk |= ((unsigned)c[0]) << k;
        pk |= ((unsigned)c[1]) << (8 + k);
        pk |= ((unsigned)c[2]) << (16 + k);
        pk |= ((unsigned)c[3]) << (24 + k);
    }
    packed[g] = pk;
}

// One kernel, 5 independent slices: y=0 edge loss, y=1..4 sal tensor y-1.
__global__ __launch_bounds__(THREADS, 3) void k_main(
        const float* __restrict__ up_edge,
        const float* __restrict__ up_sal,
        const float* __restrict__ up_sal_f,
        const float* __restrict__ target,
        const unsigned int* __restrict__ packed,
        double* __restrict__ acc,            // [0]=S_pos,[1]=S_neg,[2]=sal_l
        unsigned int* __restrict__ npos) {
    int g = blockIdx.x * THREADS + threadIdx.x;   // pixel-group
    int y = blockIdx.y;
    int b = g / IMG4;
    int r4 = g - b * IMG4;

    unsigned int pk = packed[g];
    unsigned int byte_[4];
    f4 em4;
    #pragma unroll
    for (int j = 0; j < 4; j++) {
        unsigned int by = (pk >> (8 * j)) & 0xffu;
        byte_[j] = by;
        em4[j] = (by != 0u && by != 0xffu) ? 1.0f : 0.0f;
    }

    if (y == 0) {
        // ---- edge slice: weight-factored bce2d_new over 3 logit maps ----
        f4 x[3];
        #pragma unroll
        for (int i = 0; i < 3; i++)
            x[i] = *(const f4*)(up_edge + (size_t)i * NPIX + 4 * (size_t)g);
        float sp = 0.0f, sn = 0.0f; int cnt = 0;
        #pragma unroll
        for (int j = 0; j < 4; j++) {
            float em = em4[j], ce = 0.0f;
            #pragma unroll
            for (int i = 0; i < 3; i++) {
                float xx = x[i][j];
                ce += fmaxf(xx, 0.0f) - xx * em + __logf(1.0f + __expf(-fabsf(xx)));
            }
            sp += em * ce;
            sn += (1.0f - em) * ce;
            cnt += (int)em;
        }
        sp = wave_reduce_f(sp);
        sn = wave_reduce_f(sn);
        cnt = wave_reduce_i(cnt);
        __shared__ float smp[4], smn[4];
        __shared__ int smc[4];
        int lane = threadIdx.x & 63, wid = threadIdx.x >> 6;
        if (lane == 0) { smp[wid] = sp; smn[wid] = sn; smc[wid] = cnt; }
        __syncthreads();
        if (threadIdx.x == 0) {
            atomicAdd(acc + 0, (double)(smp[0] + smp[1] + smp[2] + smp[3]));
            atomicAdd(acc + 1, (double)(smn[0] + smn[1] + smn[2] + smn[3]));
            atomicAdd(npos, (unsigned int)(smc[0] + smc[1] + smc[2] + smc[3]));
        }
        return;
    }

    // ---- sal slice for tensor s4 = y-1, f4-vectorized over j ----
    int s4 = y - 1;
    int h  = r4 / WB;
    int wb = r4 - h * WB;
    int ro = 4 * wb;
    const float* tb = (s4 < 2) ? (up_sal + (size_t)s4 * 8 * NPIX)
                               : (up_sal_f + (size_t)(s4 - 2) * 8 * NPIX);
    const float* base = tb + (size_t)b * 8 * IMG;

    f4 tgt = *(const f4*)(target + 4 * (size_t)g);
    float cmL = (wb != 0)      ? 1.0f : 0.0f;
    float cmR = (wb != WB - 1) ? 1.0f : 0.0f;

    const int drs[8] = {-1, -1, -1,  0, 0,  1, 1, 1};
    const int dcs[8] = {-1,  0,  1, -1, 1, -1, 0, 1};

    // ---- LOAD CLUSTER: all 17 wide loads issued before any compute ----
    f4 xc[8], xn[8];
    float hok[8];
    #pragma unroll
    for (int k = 0; k < 8; k++) {
        xc[k] = *(const f4*)(base + k * IMG + 4 * r4);      // 16B-aligned
        int h2  = h + drs[k];
        int h2c = min(max(h2, 0), HH - 1);
        int off = (7 - k) * IMG + h2c * WW + ro + dcs[k];   // 32-bit
        off = max(off, 0);
        off = min(off, 8 * IMG - 4);
        xn[k] = loadu4(base + off);
        hok[k] = ((unsigned)h2 < (unsigned)HH) ? 1.0f : 0.0f;
    }
    // Nothing may be scheduled across this point: loads cannot be sunk
    // into the compute loop -> 17 requests in flight per thread.
    __builtin_amdgcn_sched_barrier(0);

    f4 vsum = (f4)0.0f, vmin4 = (f4)1e30f, vb = (f4)0.0f, pb = (f4)0.0f;
    #pragma unroll
    for (int k = 0; k < 8; k++) {
        f4 tm;
        #pragma unroll
        for (int j = 0; j < 4; j++) tm[j] = (float)((byte_[j] >> k) & 1u);
        f4 ok4 = (f4){hok[k], hok[k], hok[k], hok[k]};
        if (dcs[k] == -1) ok4[0] *= cmL;
        if (dcs[k] ==  1) ok4[3] *= cmR;

        f4 e  = exp4(-xc[k]);
        f4 q1 = e + 1.0f;
        f4 sc = log4(q1);                 // -log sigmoid(xc)
        f4 en = exp4(-xn[k]);
        f4 q  = q1 * (en + 1.0f);
        f4 v  = ok4 * rcp4(q);            // vote = sig(xc)*sig(xn)*mask

        vsum += v;
        vmin4 = min4(vmin4, v);
        // t=1: -log v ; t=0: -log(1-v) — arithmetic select, one log
        f4 arg = (1.0f - v) + tm * (2.0f * v - 1.0f);
        vb += min4s(-log4(arg), 100.0f);
        pb += min4s(sc + (1.0f - tm) * xc[k], 100.0f);
    }

    f4 glo = vsum * 0.125f;
    f4 dec = glo + em4 * ((1.0f - vmin4) - glo);
    f4 lgd  = max4s(log4(dec), -100.0f);
    f4 lg1d = max4s(log4(1.0f - dec), -100.0f);
    f4 lf = -(tgt * lgd + (1.0f - tgt) * lg1d) + 0.2f * vb + 0.8f * pb;
    float local = lf[0] + lf[1] + lf[2] + lf[3];
    block_acc(local, acc + 2);
}

__global__ void k_final(const double* __restrict__ acc,
                        const unsigned int* __restrict__ npos,
                        float* __restrict__ out) {
    if (threadIdx.x == 0) {
        double np_  = (double)(*npos);
        double tot  = (double)NPIX;
        double nn   = tot - np_;
        double wpos = nn / tot;
        double wneg = 1.1 * np_ / tot;
        double e  = wpos * acc[0] + wneg * acc[1];
        double sl = acc[2];
        double l  = e + sl;
        out[0] = (float)l;
        out[1] = (float)e;
        out[2] = (float)sl;
        out[3] = (float)l;
    }
}

extern "C" void kernel_launch(void* const* d_in, const int* in_sizes, int n_in,
                              void* d_out, int out_size, void* d_ws, size_t ws_size,
                              hipStream_t stream) {
    const float* up_edge  = (const float*)d_in[0];  // [3,B,1,H,W]
    const float* up_sal   = (const float*)d_in[1];  // [2,B,8,H,W]
    const float* up_sal_f = (const float*)d_in[2];  // [2,B,8,H,W]
    const float* target   = (const float*)d_in[3];  // [B,1,H,W]
    const int*   con      = (const int*)d_in[4];    // [B,8,H,W]
    float* out = (float*)d_out;

    // ws: acc[0..2] doubles (S_pos, S_neg, sal_l); npos uint at +24;
    //     packed con plane (NG uints) at +64
    double*       acc    = (double*)d_ws;
    unsigned int* npos   = (unsigned int*)((char*)d_ws + 24);
    unsigned int* packed = (unsigned int*)((char*)d_ws + 64);

    k_pack<<<GBLK, THREADS, 0, stream>>>(con, packed, acc, npos);
    k_main<<<dim3(GBLK, 5), THREADS, 0, stream>>>(up_edge, up_sal, up_sal_f,
                                                  target, packed, acc, npos);
    k_final<<<1, 64, 0, stream>>>(acc, npos, out);
}